// Round 5
// baseline (672.228 us; speedup 1.0000x reference)
//
#include <hip/hip_runtime.h>
#include <math.h>

// TreeLSTM MI355X — R17: R16's epilogue∥kc-loop pipeline extended with a
// leaf-GATHER variant so lvl8 (haveLeafC==0 in this harness — R16's top
// dispatch proved it) runs pipelined. Per kc-phase the pipe now prefetches
// the 2 type-indices + 4 WxV h16 values for prev-cb parent 'kc' into a
// 2-deep register ring (issued right after the B-DMA issue => full phase of
// latency cover for the dependent index->WxV chain), and consumes slot kc-1
// in the VALU chunk placed in the DMA-drain window before the MFMA cluster.
// Prev-cb bi/bu biases kept for the leaf cell math. Basic kernel now only
// lvl<=5. Model (R12-R16): pipes serialized — epilogue VALU 160k cy + LDS
// 123k + MFMA 80k ≈ total; lvl8's gather epilogue is the heaviest (2 L2/HBM
// gather chains + 6 extra trans per cell), so hiding it there pays most.
// ws: 235.4 MB base; +67.1 MB leafC if ws_size >= 303 MB.

typedef _Float16 h16;
typedef h16 f16x8 __attribute__((ext_vector_type(8)));
typedef h16 h16x2 __attribute__((ext_vector_type(2)));
typedef float f32x4 __attribute__((ext_vector_type(4)));

#define HS 256
#define NTREE 1023
#define B2 256

#define DMA16(gp, lp) __builtin_amdgcn_global_load_lds( \
    (const __attribute__((address_space(1))) void*)(gp), \
    (__attribute__((address_space(3))) void*)(lp), 16, 0, 0)

__device__ __forceinline__ float sigf(float x){
  return __builtin_amdgcn_rcpf(1.0f + exp2f(x * -1.44269504f));
}
__device__ __forceinline__ float tanh_fast(float x){
  return 2.0f*__builtin_amdgcn_rcpf(1.0f + exp2f(x * -2.88539008f)) - 1.0f;
}
// sigmoid(a)*tanh(b) in 3 trans (exp2,exp2,rcp). Clamp avoids E2=inf -> NaN.
__device__ __forceinline__ float sig_mul_tanh(float a, float b){
  const float E1 = exp2f(a * -1.44269504f);
  const float E2 = exp2f(fminf(b * -2.88539008f, 126.0f));
  return (1.0f - E2) * __builtin_amdgcn_rcpf((1.0f + E1) * (1.0f + E2));
}

// ------------- convert fp32 -> fp16 (emb, Ufw, Uiou, Wiou) + zero rep -------
__global__ __launch_bounds__(256) void convert_all(const float* __restrict__ emb,
    const float* __restrict__ Ufw, const float* __restrict__ Uiou,
    const float* __restrict__ Wiou, h16* __restrict__ emb16,
    h16* __restrict__ W16, h16* __restrict__ Wx16, float* __restrict__ rep){
  if (blockIdx.x < 64)
    ((float4*)rep)[blockIdx.x*256 + threadIdx.x] = make_float4(0.f,0.f,0.f,0.f);
  const size_t i0 = ((size_t)blockIdx.x*256 + threadIdx.x)*8;
  const float* src; h16* dst; size_t off;
  if (i0 < 8192000UL){ src = emb;  dst = emb16;       off = i0; }
  else if (i0 < 8257536UL){ src = Ufw;  dst = W16;        off = i0 - 8192000UL; }
  else if (i0 < 8454144UL){ src = Uiou; dst = W16+65536;  off = i0 - 8257536UL; }
  else               { src = Wiou; dst = Wx16;       off = i0 - 8454144UL; }
  const float4 v0 = *(const float4*)&src[off];
  const float4 v1 = *(const float4*)&src[off+4];
  f16x8 o;
  o[0]=(h16)v0.x; o[1]=(h16)v0.y; o[2]=(h16)v0.z; o[3]=(h16)v0.w;
  o[4]=(h16)v1.x; o[5]=(h16)v1.y; o[6]=(h16)v1.z; o[7]=(h16)v1.w;
  *(f16x8*)&dst[off] = o;
}

// ------------- swizzle W16 into MFMA fragment order -------------
__global__ __launch_bounds__(256) void swizzle_w(const h16* __restrict__ W16,
    h16* __restrict__ Wfrag){
  const int tid = blockIdx.x*256 + threadIdx.x;   // 0..65535
  const int lane = tid & 63;
  const int f    = (tid >> 6) & 15;
  const int kc   = (tid >> 10) & 7;
  const int cb   = tid >> 13;
  const int g = f >> 2, cf = f & 3;
  const int row = g*256 + cb*64 + cf*16 + (lane & 15);
  const int col = kc*32 + (lane >> 4)*8;
  const f16x8 v = *(const f16x8*)&W16[(size_t)row*256 + col];
  *(f16x8*)&Wfrag[(size_t)tid*8] = v;
}

// ------------- WxV = emb16 @ Wx16^T : M=32000, N=768, K=256 (MFMA) -------------
__global__ __launch_bounds__(256) void wxv_mfma(const h16* __restrict__ emb16,
    const h16* __restrict__ Wx16, h16* __restrict__ WxV){
  __shared__ h16 As[64*40];
  __shared__ h16 Bs[64*40];
  const int t = threadIdx.x, lane = t & 63, wave = t >> 6;
  const int q = lane >> 4, li = lane & 15;
  const int waveR = wave & 1, waveC = wave >> 1;
  const int bm = blockIdx.x*64, bn = blockIdx.y*64;
  const size_t aAddr = ((size_t)(bm + (t>>2)))*256 + (t&3)*8;
  const size_t bAddr = ((size_t)(bn + (t>>2)))*256 + (t&3)*8;
  const int ldsOff = (t>>2)*40 + (t&3)*8;
  f32x4 acc[2][2] = {};
  for (int k0 = 0; k0 < 256; k0 += 32){
    const f16x8 a = *(const f16x8*)&emb16[aAddr + k0];
    const f16x8 b = *(const f16x8*)&Wx16[bAddr + k0];
    __syncthreads();
    *(f16x8*)&As[ldsOff] = a;
    *(f16x8*)&Bs[ldsOff] = b;
    __syncthreads();
    #pragma unroll
    for (int rt=0; rt<2; ++rt){
      const f16x8 av = *(const f16x8*)&As[(waveR*32 + rt*16 + li)*40 + q*8];
      #pragma unroll
      for (int ct=0; ct<2; ++ct){
        const f16x8 bv = *(const f16x8*)&Bs[(waveC*32 + ct*16 + li)*40 + q*8];
        acc[rt][ct] = __builtin_amdgcn_mfma_f32_16x16x32_f16(av, bv, acc[rt][ct], 0,0,0);
      }
    }
  }
  #pragma unroll
  for (int rt=0; rt<2; ++rt)
    #pragma unroll
    for (int ct=0; ct<2; ++ct){
      const int col = bn + waveC*32 + ct*16 + li;
      #pragma unroll
      for (int reg=0; reg<4; ++reg){
        const int row = bm + waveR*32 + rt*16 + q*4 + reg;
        WxV[(size_t)row*768 + col] = (h16)acc[rt][ct][reg];
      }
    }
}

// ------------- leaves: gather WxV, cell, write h (+opt c), fold rep --------
__global__ __launch_bounds__(256) void leaf_kernel(const int* __restrict__ t1,
    const int* __restrict__ t2, const h16* __restrict__ WxV,
    const float* __restrict__ biou, h16* __restrict__ leafH,
    h16* __restrict__ leafC, int haveLeafC, float* __restrict__ rep){
  const int r = blockIdx.y, jg = blockIdx.x, k = threadIdx.x;
  const int* tp = (r < 128) ? t1 : t2;
  const int b = r & 127;
  const float bi = biou[k], bo = biou[256+k], bu = biou[512+k];
  float s = 0.f;
  for (int jj=0; jj<64; ++jj){
    const int leafIdx = jg*64 + jj;
    const size_t v = (size_t)tp[b*NTREE + 511 + leafIdx];
    const float vi = (float)WxV[v*768 + k] + bi;
    const float vo = (float)WxV[v*768 + 256 + k] + bo;
    const float vu = (float)WxV[v*768 + 512 + k] + bu;
    const float c = sigf(vi) * tanh_fast(vu);
    const float h = sigf(vo) * tanh_fast(c);
    const size_t o = ((size_t)r*512 + leafIdx)*HS + k;
    leafH[o] = (h16)h;
    if (haveLeafC) leafC[o] = (h16)c;
    s += h;
  }
  atomicAdd(&rep[r*HS + k], s);
}

// ------------- R12 kernel (proven) — small levels (lvl<=5) -------------
__global__ __launch_bounds__(256,3) void level_mfma_basic(
    const h16* __restrict__ hChild, const h16* __restrict__ cChild,
    const h16* __restrict__ Wfrag,   // [cb=4][kc=8][f=16][lane=64][8]
    const float* __restrict__ biou, const float* __restrict__ Ufb,
    h16* __restrict__ hUp, h16* __restrict__ cPar,
    int log2n){
  const int n = 1 << log2n;
  const int mask2 = 2*n - 1;
  const int strideR = 511;
  const int childBase = mask2;
  __shared__ h16 ldsA[4*8*64*8];   // 32 KB
  __shared__ h16 ldsB[16*64*8];    // 16 KB
  const int t = threadIdx.x, w = t >> 6, l = t & 63;
  const int q = l >> 4, li = l & 15;
  const int waveR = w & 1, waveC = w >> 1;
  const int bx = blockIdx.x;

  {
    const int grow = bx*64 + w*16 + li;
    const int rr = grow >> (log2n + 1);
    const size_t abase = ((size_t)rr*strideR + childBase + (grow & mask2))*256;
    #pragma unroll
    for (int kc=0; kc<8; ++kc)
      DMA16(hChild + abase + kc*32 + q*8, &ldsA[(w*8 + kc)*512]);
  }

  {
    const int cbi = blockIdx.y;
    const int colBase = cbi*64;
    const h16* wfBase = Wfrag + (size_t)cbi*8*16*512 + (size_t)l*8;

    #pragma unroll
    for (int i=0; i<4; ++i)
      DMA16(wfBase + ((size_t)(w*4 + i))*512, &ldsB[(w*4 + i)*512]);
    __syncthreads();

    f32x4 acc[4][2][2] = {};
    #pragma unroll
    for (int kc=0; kc<8; ++kc){
      f16x8 aF[2], bF[4][2];
      #pragma unroll
      for (int rt=0; rt<2; ++rt)
        aF[rt] = *(const f16x8*)&ldsA[(((waveR*2 + rt)*8 + kc)*64 + l)*8];
      #pragma unroll
      for (int g=0; g<4; ++g)
        #pragma unroll
        for (int ct=0; ct<2; ++ct)
          bF[g][ct] = *(const f16x8*)&ldsB[((g*4 + waveC*2 + ct)*64 + l)*8];
      __syncthreads();
      if (kc < 7){
        #pragma unroll
        for (int i=0; i<4; ++i)
          DMA16(wfBase + ((size_t)(kc+1)*16 + w*4 + i)*512,
                &ldsB[(w*4 + i)*512]);
      }
      #pragma unroll
      for (int g=0; g<4; ++g)
        #pragma unroll
        for (int rt=0; rt<2; ++rt)
          #pragma unroll
          for (int ct=0; ct<2; ++ct)
            acc[g][rt][ct] = __builtin_amdgcn_mfma_f32_16x16x32_f16(
                aF[rt], bF[g][ct], acc[g][rt][ct], 0,0,0);
      __syncthreads();
    }

    #pragma unroll
    for (int ct=0; ct<2; ++ct){
      const int c = colBase + waveC*32 + ct*16 + li;
      const float fb  = Ufb[c];
      const float bi_ = biou[c], bo_ = biou[256+c], bu_ = biou[512+c];
      #pragma unroll
      for (int rt=0; rt<2; ++rt){
        #pragma unroll
        for (int pp=0; pp<2; ++pp){
          const int crel = waveR*32 + rt*16 + q*4 + 2*pp;
          const int m = bx*32 + (crel >> 1);
          const int rr2 = m >> log2n;
          const int jn = m & (n - 1);
          const float fl = sigf(acc[0][rt][ct][2*pp]   + fb);
          const float fr = sigf(acc[0][rt][ct][2*pp+1] + fb);
          const float iv = acc[1][rt][ct][2*pp] + acc[1][rt][ct][2*pp+1] + bi_;
          const float ov = acc[2][rt][ct][2*pp] + acc[2][rt][ct][2*pp+1] + bo_;
          const float uv = acc[3][rt][ct][2*pp] + acc[3][rt][ct][2*pp+1] + bu_;
          const float cl = (float)cChild[(size_t)(bx*64 + crel)*256 + c];
          const float cr = (float)cChild[(size_t)(bx*64 + crel + 1)*256 + c];
          const float cnew = sigf(iv)*tanh_fast(uv) + fl*cl + fr*cr;
          const float hnew = sigf(ov)*tanh_fast(cnew);
          hUp [((size_t)rr2*511 + (n-1) + jn)*256 + c] = (h16)hnew;
          cPar[((size_t)m)*256 + c] = (h16)cnew;
        }
      }
    }
  }
}

// ------------- pipelined kernel: epilogue(cb) runs inside kc-loop(cb+1) -----
// GATHER=true: leaf level without leafC — prev-cb children fetched via
// types->WxV prefetch ring (2-deep), leaf cell math done in the chunk.
template<bool GATHER>
__global__ __launch_bounds__(256,3) void level_mfma_pipe(
    const h16* __restrict__ hChild, const h16* __restrict__ cChild,
    const h16* __restrict__ Wfrag,   // [cb=4][kc=8][f=16][lane=64][8]
    const h16* __restrict__ WxV,
    const int* __restrict__ t1, const int* __restrict__ t2,
    const float* __restrict__ biou, const float* __restrict__ Ufb,
    h16* __restrict__ hUp, h16* __restrict__ cPar,
    int log2n, int leafLvl){
  const int n = 1 << log2n;
  const int mask2 = 2*n - 1;
  const int strideR = leafLvl ? 512 : 511;
  const int childBase = leafLvl ? 0 : mask2;
  __shared__ h16 ldsA[4*8*64*8];   // 32 KB
  __shared__ h16 ldsB[16*64*8];    // 16 KB
  const int t = threadIdx.x, w = t >> 6, l = t & 63;
  const int q = l >> 4, li = l & 15;
  const int waveR = w & 1, waveC = w >> 1;
  const int bx = blockIdx.x;

  // ---- stage A once ----
  {
    const int grow = bx*64 + w*16 + li;
    const int rr = grow >> (log2n + 1);
    const size_t abase = ((size_t)rr*strideR + childBase + (grow & mask2))*256;
    #pragma unroll
    for (int kc=0; kc<8; ++kc)
      DMA16(hChild + abase + kc*32 + q*8, &ldsA[(w*8 + kc)*512]);
  }

  // pipeline state: prev cb's pre-activations (bias folded). e = ct*4+rt*2+pp
  h16x2 pFlFr[8];   // sigmoid inputs for f-gates
  h16x2 pIO[8];     // sigmoid inputs i,o
  float pUv[8];     // tanh input u — f32
  float bFb[2], bBi[2], bBo[2], bBu[2];
  float pBi[2], pBu[2];      // prev-cb bi/bu (leaf-gather cell math)
  h16x2 rCC[2];              // non-gather ring: (cl, cr)
  h16x2 rL[2], rR[2];        // gather ring: (w_i, w_u) left / right child
  int prevCol = 0;

  auto chunk = [&](int e, float cl, float cr){
    const int ct = e>>2, rt = (e>>1)&1, pp = e&1;
    const int crel = waveR*32 + rt*16 + q*4 + 2*pp;
    const int m = bx*32 + (crel >> 1);
    const int rr2 = m >> log2n;
    const int jn = m & (n - 1);
    const int c = prevCol + waveC*32 + ct*16 + li;
    const float fl = sigf((float)pFlFr[e][0]);
    const float fr = sigf((float)pFlFr[e][1]);
    const float cnew = sig_mul_tanh((float)pIO[e][0], pUv[e]) + fl*cl + fr*cr;
    const float hnew = sig_mul_tanh((float)pIO[e][1], cnew);
    hUp [((size_t)rr2*511 + (n-1) + jn)*256 + c] = (h16)hnew;
    cPar[(size_t)m*256 + c] = (h16)cnew;
  };
  auto ringCl = [&](int e)->float{   // consume ring slot e&1 -> cl
    if (GATHER)
      return sig_mul_tanh((float)rL[e&1][0] + pBi[e>>2],
                          (float)rL[e&1][1] + pBu[e>>2]);
    return (float)rCC[e&1][0];
  };
  auto ringCr = [&](int e)->float{
    if (GATHER)
      return sig_mul_tanh((float)rR[e&1][0] + pBi[e>>2],
                          (float)rR[e&1][1] + pBu[e>>2]);
    return (float)rCC[e&1][1];
  };
  auto prefetch = [&](int e){        // load prev-cb parent e's child data
    const int rt2=(e>>1)&1, pp2=e&1, ct2=e>>2;
    const int crel = waveR*32 + rt2*16 + q*4 + 2*pp2;
    const int cc_ = prevCol + waveC*32 + ct2*16 + li;
    if (GATHER){
      const int m = bx*32 + (crel >> 1);
      const int rr2 = m >> log2n;
      const int jn = m & (n - 1);
      const int* tp = (rr2 < 128) ? t1 : t2;
      const int b = rr2 & 127;
      const size_t vl = (size_t)tp[b*NTREE + 511 + 2*jn];
      const size_t vr = (size_t)tp[b*NTREE + 512 + 2*jn];
      h16x2 L, R;
      L[0] = WxV[vl*768 + cc_]; L[1] = WxV[vl*768 + 512 + cc_];
      R[0] = WxV[vr*768 + cc_]; R[1] = WxV[vr*768 + 512 + cc_];
      rL[e&1] = L; rR[e&1] = R;
    } else {
      const int cgl = bx*64 + crel;
      h16x2 C;
      C[0] = cChild[(size_t)cgl*256 + cc_];
      C[1] = cChild[(size_t)(cgl+1)*256 + cc_];
      rCC[e&1] = C;
    }
  };

  for (int cb=0; cb<4; ++cb){
    const int colBase = cb*64;
    const h16* wfBase = Wfrag + (size_t)cb*8*16*512 + (size_t)l*8;
    const bool havePrev = (cb > 0);

    #pragma unroll
    for (int bc=0; bc<2; ++bc){
      const int c = colBase + waveC*32 + bc*16 + li;
      bFb[bc] = Ufb[c];
      bBi[bc] = biou[c]; bBo[bc] = biou[256+c]; bBu[bc] = biou[512+c];
    }
    #pragma unroll
    for (int i=0; i<4; ++i)
      DMA16(wfBase + ((size_t)(w*4 + i))*512, &ldsB[(w*4 + i)*512]);
    __syncthreads();   // drains A (cb0), B(0), prev stores/loads

    f32x4 acc[4][2][2] = {};
    #pragma unroll
    for (int kc=0; kc<8; ++kc){
      f16x8 aF[2], bF[4][2];
      #pragma unroll
      for (int rt=0; rt<2; ++rt)
        aF[rt] = *(const f16x8*)&ldsA[(((waveR*2 + rt)*8 + kc)*64 + l)*8];
      #pragma unroll
      for (int g=0; g<4; ++g)
        #pragma unroll
        for (int ct=0; ct<2; ++ct)
          bF[g][ct] = *(const f16x8*)&ldsB[((g*4 + waveC*2 + ct)*64 + l)*8];
      __syncthreads();   // sync1: reads done
      if (kc < 7){
        #pragma unroll
        for (int i=0; i<4; ++i)
          DMA16(wfBase + ((size_t)(kc+1)*16 + w*4 + i)*512,
                &ldsB[(w*4 + i)*512]);
      }
      if (havePrev){
        prefetch(kc);                       // ring slot kc&1, used next phase
        if (kc >= 1)
          chunk(kc-1, ringCl(kc-1), ringCr(kc-1));   // DMA-drain window VALU
      }
      #pragma unroll
      for (int g=0; g<4; ++g)
        #pragma unroll
        for (int rt=0; rt<2; ++rt)
          #pragma unroll
          for (int ct=0; ct<2; ++ct)
            acc[g][rt][ct] = __builtin_amdgcn_mfma_f32_16x16x32_f16(
                aF[rt], bF[g][ct], acc[g][rt][ct], 0,0,0);
      __syncthreads();   // sync2: drains B(kc+1) DMA + ring loads + stores
    }

    if (havePrev)
      chunk(7, ringCl(7), ringCr(7));

    // sib-add + bias fold: compress acc(64 regs) -> pre-acts (~24 regs)
    #pragma unroll
    for (int ep=0; ep<4; ++ep){
      const int ct = ep>>1, rt = ep&1;
      #pragma unroll
      for (int pp=0; pp<2; ++pp){
        const int e = ep*2 + pp;   // = ct*4 + rt*2 + pp  (ep = ct*2+rt)
        h16x2 v;
        v[0] = (h16)(acc[0][rt][ct][2*pp]   + bFb[ct]);
        v[1] = (h16)(acc[0][rt][ct][2*pp+1] + bFb[ct]);
        pFlFr[e] = v;
        h16x2 u;
        u[0] = (h16)(acc[1][rt][ct][2*pp] + acc[1][rt][ct][2*pp+1] + bBi[ct]);
        u[1] = (h16)(acc[2][rt][ct][2*pp] + acc[2][rt][ct][2*pp+1] + bBo[ct]);
        pIO[e] = u;
        pUv[e] = acc[3][rt][ct][2*pp] + acc[3][rt][ct][2*pp+1] + bBu[ct];
      }
    }
    pBi[0] = bBi[0]; pBi[1] = bBi[1];
    pBu[0] = bBu[0]; pBu[1] = bBu[1];
    prevCol = colBase;
  }

  // tail: epilogue for cb=3 (serial, once per block)
  #pragma unroll
  for (int e2=0; e2<8; e2+=2){
    prefetch(e2); prefetch(e2+1);
    chunk(e2,   ringCl(e2),   ringCr(e2));
    chunk(e2+1, ringCl(e2+1), ringCr(e2+1));
  }
}

// ------------- rep accumulation (internal nodes, hUp) -------------
__global__ __launch_bounds__(256) void rep_accum(const h16* __restrict__ H,
    float* __restrict__ rep, int nrows, int chunk){
  const int r = blockIdx.y, k = threadIdx.x;
  const int n0 = blockIdx.x * chunk;
  int n1 = n0 + chunk; if (n1 > nrows) n1 = nrows;
  float s = 0.f;
  for (int nd = n0; nd < n1; ++nd)
    s += (float)H[((size_t)r*nrows + nd)*HS + k];
  atomicAdd(&rep[r*HS + k], s);
}

// ------------- classifier -------------
__global__ __launch_bounds__(256) void cls_kernel(const float* __restrict__ rep,
    const float* __restrict__ clsw, const float* __restrict__ clsb,
    float* __restrict__ out){
  const int b = blockIdx.x, k = threadIdx.x;
  const float d = fabsf(rep[b*HS + k] - rep[(128+b)*HS + k]) * (1.0f/1023.0f);
  __shared__ float r0[256], r1[256];
  r0[k] = d * clsw[k];
  r1[k] = d * clsw[HS + k];
  __syncthreads();
  for (int off = 128; off > 0; off >>= 1){
    if (k < off){ r0[k] += r0[k+off]; r1[k] += r1[k+off]; }
    __syncthreads();
  }
  if (k == 0){
    out[b*2 + 0] = r0[0] + clsb[0];
    out[b*2 + 1] = r1[0] + clsb[1];
  }
}

extern "C" void kernel_launch(void* const* d_in, const int* in_sizes, int n_in,
                              void* d_out, int out_size, void* d_ws, size_t ws_size,
                              hipStream_t stream){
  const int*   types1 = (const int*)d_in[0];
  const int*   types2 = (const int*)d_in[1];
  const float* emb    = (const float*)d_in[2];
  const float* Wiou   = (const float*)d_in[3];
  const float* Uiou   = (const float*)d_in[4];
  const float* biou   = (const float*)d_in[5];
  const float* Ufw    = (const float*)d_in[6];
  const float* Ufb    = (const float*)d_in[7];
  const float* clsw   = (const float*)d_in[8];
  const float* clsb   = (const float*)d_in[9];
  float* out = (float*)d_out;

  h16* WxV   = (h16*)d_ws;                        // 24,576,000
  h16* leafH = WxV   + 24576000UL;                // 33,554,432
  h16* hUp   = leafH + 33554432UL;                // 33,488,896
  h16* cA    = hUp   + 33488896UL;                // 16,777,216
  h16* cB    = cA    + 16777216UL;                //  8,388,608
  h16* emb16 = cB;                                //  8,192,000 (overlay on cB)
  h16* Wx16  = cB + 8192000UL;                    //    196,608 (overlay on cB)
  float* rep = (float*)(cB + 8388608UL);          //     65,536 fp32
  h16* W16   = (h16*)(rep + 65536UL);             //    262,144
  h16* Wfrag = W16 + 262144UL;                    //    524,288 (1 MB)
  h16* leafC = Wfrag + 524288UL;                  // 33,554,432 (optional, 67 MB)
  const int haveLeafC = (ws_size >= 302600000UL) ? 1 : 0;

  convert_all<<<4224, 256, 0, stream>>>(emb, Ufw, Uiou, Wiou, emb16, W16, Wx16, rep);
  swizzle_w<<<256, 256, 0, stream>>>(W16, Wfrag);
  wxv_mfma<<<dim3(500,12), 256, 0, stream>>>(emb16, Wx16, WxV);
  leaf_kernel<<<dim3(8, B2), 256, 0, stream>>>(types1, types2, WxV, biou,
                                               leafH, leafC, haveLeafC, rep);

  const h16* cprev = nullptr;
  for (int lvl = 8; lvl >= 0; --lvl){
    const int children = 512 << lvl;        // B2 * 2n
    h16* cout = ((8 - lvl) & 1) ? cB : cA;
    const h16* cin = (lvl == 8) ? (haveLeafC ? leafC : nullptr) : cprev;
    const h16* hin = (lvl == 8) ? leafH : hUp;
    if (lvl >= 6){
      if (lvl == 8 && !haveLeafC)
        level_mfma_pipe<true><<<dim3(children/64, 1), 256, 0, stream>>>(
            hin, nullptr, Wfrag, WxV, types1, types2, biou, Ufb,
            hUp, cout, lvl, 1);
      else
        level_mfma_pipe<false><<<dim3(children/64, 1), 256, 0, stream>>>(
            hin, cin, Wfrag, WxV, types1, types2, biou, Ufb,
            hUp, cout, lvl, (lvl == 8) ? 1 : 0);
    } else {
      level_mfma_basic<<<dim3(children/64, 4), 256, 0, stream>>>(
          hin, cin, Wfrag, biou, Ufb, hUp, cout, lvl);
    }
    cprev = cout;
  }
  rep_accum<<<dim3(4, B2), 256, 0, stream>>>(hUp, rep, 511, 128);
  cls_kernel<<<128, 256, 0, stream>>>(rep, clsw, clsb, out);
}

// Round 6
// 514.932 us; speedup vs baseline: 1.3055x; 1.3055x over previous
//
#include <hip/hip_runtime.h>
#include <math.h>

// TreeLSTM MI355X — R18: leafC in the base workspace budget (overlay layout).
// R17 post-mortem: scattering the epilogue across kc-phases doubled WRITE
// (74->145MB — broke 64B write-combining; partial-line stores forced line
// fills => FETCH 100->255MB) and ring gathers missed to HBM inside barrier
// phases. R13/R14/R16/R17 all prove: this kernel rejects schedule surgery.
// R18 removes WORK instead: lvl8's epilogue re-gathered WxV + recomputed every
// leaf cell (~20 trans + 4 scattered loads per parent-col) ONLY because leafC
// didn't fit. It fits: WxV (49MB) is dead after leaf_kernel once lvl8 stops
// gathering -> holds hUp's lvl8 half; leafC region holds hUp's lvl<=7 half
// (dead after lvl8); W16 overlays leafH. hUp becomes node-major [nd][tree][col]
// so the halves split at nd=255. cChild indexing unchanged (instance-linear).
// Level kernel = exact R12 schedule (proven 158us), single variant (no
// template co-compilation noise), gather path deleted, 3-trans sig_mul_tanh.
// New total: 235.01 MB < proven 235.40 MB budget.

typedef _Float16 h16;
typedef h16 f16x8 __attribute__((ext_vector_type(8)));
typedef float f32x4 __attribute__((ext_vector_type(4)));

#define HS 256
#define NTREE 1023
#define B2 256

#define DMA16(gp, lp) __builtin_amdgcn_global_load_lds( \
    (const __attribute__((address_space(1))) void*)(gp), \
    (__attribute__((address_space(3))) void*)(lp), 16, 0, 0)

__device__ __forceinline__ float sigf(float x){
  return __builtin_amdgcn_rcpf(1.0f + exp2f(x * -1.44269504f));
}
__device__ __forceinline__ float tanh_fast(float x){
  return 2.0f*__builtin_amdgcn_rcpf(1.0f + exp2f(x * -2.88539008f)) - 1.0f;
}
// sigmoid(a)*tanh(b) in 3 trans (exp2,exp2,rcp). Clamp avoids E2=inf -> NaN.
__device__ __forceinline__ float sig_mul_tanh(float a, float b){
  const float E1 = exp2f(a * -1.44269504f);
  const float E2 = exp2f(fminf(b * -2.88539008f, 126.0f));
  return (1.0f - E2) * __builtin_amdgcn_rcpf((1.0f + E1) * (1.0f + E2));
}

// ------------- convert fp32 -> fp16 (emb, Ufw, Uiou, Wiou) + zero rep -------
__global__ __launch_bounds__(256) void convert_all(const float* __restrict__ emb,
    const float* __restrict__ Ufw, const float* __restrict__ Uiou,
    const float* __restrict__ Wiou, h16* __restrict__ emb16,
    h16* __restrict__ W16, h16* __restrict__ Wx16, float* __restrict__ rep){
  if (blockIdx.x < 64)
    ((float4*)rep)[blockIdx.x*256 + threadIdx.x] = make_float4(0.f,0.f,0.f,0.f);
  const size_t i0 = ((size_t)blockIdx.x*256 + threadIdx.x)*8;
  const float* src; h16* dst; size_t off;
  if (i0 < 8192000UL){ src = emb;  dst = emb16;       off = i0; }
  else if (i0 < 8257536UL){ src = Ufw;  dst = W16;        off = i0 - 8192000UL; }
  else if (i0 < 8454144UL){ src = Uiou; dst = W16+65536;  off = i0 - 8257536UL; }
  else               { src = Wiou; dst = Wx16;       off = i0 - 8454144UL; }
  const float4 v0 = *(const float4*)&src[off];
  const float4 v1 = *(const float4*)&src[off+4];
  f16x8 o;
  o[0]=(h16)v0.x; o[1]=(h16)v0.y; o[2]=(h16)v0.z; o[3]=(h16)v0.w;
  o[4]=(h16)v1.x; o[5]=(h16)v1.y; o[6]=(h16)v1.z; o[7]=(h16)v1.w;
  *(f16x8*)&dst[off] = o;
}

// ------------- swizzle W16 into MFMA fragment order -------------
__global__ __launch_bounds__(256) void swizzle_w(const h16* __restrict__ W16,
    h16* __restrict__ Wfrag){
  const int tid = blockIdx.x*256 + threadIdx.x;   // 0..65535
  const int lane = tid & 63;
  const int f    = (tid >> 6) & 15;
  const int kc   = (tid >> 10) & 7;
  const int cb   = tid >> 13;
  const int g = f >> 2, cf = f & 3;
  const int row = g*256 + cb*64 + cf*16 + (lane & 15);
  const int col = kc*32 + (lane >> 4)*8;
  const f16x8 v = *(const f16x8*)&W16[(size_t)row*256 + col];
  *(f16x8*)&Wfrag[(size_t)tid*8] = v;
}

// ------------- WxV = emb16 @ Wx16^T : M=32000, N=768, K=256 (MFMA) -------------
__global__ __launch_bounds__(256) void wxv_mfma(const h16* __restrict__ emb16,
    const h16* __restrict__ Wx16, h16* __restrict__ WxV){
  __shared__ h16 As[64*40];
  __shared__ h16 Bs[64*40];
  const int t = threadIdx.x, lane = t & 63, wave = t >> 6;
  const int q = lane >> 4, li = lane & 15;
  const int waveR = wave & 1, waveC = wave >> 1;
  const int bm = blockIdx.x*64, bn = blockIdx.y*64;
  const size_t aAddr = ((size_t)(bm + (t>>2)))*256 + (t&3)*8;
  const size_t bAddr = ((size_t)(bn + (t>>2)))*256 + (t&3)*8;
  const int ldsOff = (t>>2)*40 + (t&3)*8;
  f32x4 acc[2][2] = {};
  for (int k0 = 0; k0 < 256; k0 += 32){
    const f16x8 a = *(const f16x8*)&emb16[aAddr + k0];
    const f16x8 b = *(const f16x8*)&Wx16[bAddr + k0];
    __syncthreads();
    *(f16x8*)&As[ldsOff] = a;
    *(f16x8*)&Bs[ldsOff] = b;
    __syncthreads();
    #pragma unroll
    for (int rt=0; rt<2; ++rt){
      const f16x8 av = *(const f16x8*)&As[(waveR*32 + rt*16 + li)*40 + q*8];
      #pragma unroll
      for (int ct=0; ct<2; ++ct){
        const f16x8 bv = *(const f16x8*)&Bs[(waveC*32 + ct*16 + li)*40 + q*8];
        acc[rt][ct] = __builtin_amdgcn_mfma_f32_16x16x32_f16(av, bv, acc[rt][ct], 0,0,0);
      }
    }
  }
  #pragma unroll
  for (int rt=0; rt<2; ++rt)
    #pragma unroll
    for (int ct=0; ct<2; ++ct){
      const int col = bn + waveC*32 + ct*16 + li;
      #pragma unroll
      for (int reg=0; reg<4; ++reg){
        const int row = bm + waveR*32 + rt*16 + q*4 + reg;
        WxV[(size_t)row*768 + col] = (h16)acc[rt][ct][reg];
      }
    }
}

// ------------- leaves: gather WxV, cell, write h + c, fold rep --------------
__global__ __launch_bounds__(256) void leaf_kernel(const int* __restrict__ t1,
    const int* __restrict__ t2, const h16* __restrict__ WxV,
    const float* __restrict__ biou, h16* __restrict__ leafH,
    h16* __restrict__ leafC, float* __restrict__ rep){
  const int r = blockIdx.y, jg = blockIdx.x, k = threadIdx.x;
  const int* tp = (r < 128) ? t1 : t2;
  const int b = r & 127;
  const float bi = biou[k], bo = biou[256+k], bu = biou[512+k];
  float s = 0.f;
  for (int jj=0; jj<64; ++jj){
    const int leafIdx = jg*64 + jj;
    const size_t v = (size_t)tp[b*NTREE + 511 + leafIdx];
    const float vi = (float)WxV[v*768 + k] + bi;
    const float vo = (float)WxV[v*768 + 256 + k] + bo;
    const float vu = (float)WxV[v*768 + 512 + k] + bu;
    const float c = sigf(vi) * tanh_fast(vu);
    const float h = sigf(vo) * tanh_fast(c);
    const size_t o = ((size_t)r*512 + leafIdx)*HS + k;
    leafH[o] = (h16)h;
    leafC[o] = (h16)c;
    s += h;
  }
  atomicAdd(&rep[r*HS + k], s);
}

// ------------- level kernel: exact R12 schedule, no gather path -------------
// hChild: leafLvl -> leafH (instance-linear rows, addr = grow*256);
//         else    -> node-major hUp region, row = (cOff + cidx)*256 + rr.
// hUpW:   node-major output region for this level, node local = ndOff + jn.
// cChild/cPar: instance-linear (index = child instance / parent m) — unchanged.
__global__ __launch_bounds__(256,3) void level_mfma(
    const h16* __restrict__ hChild, const h16* __restrict__ cChild,
    const h16* __restrict__ Wfrag,   // [cb=4][kc=8][f=16][lane=64][8]
    const float* __restrict__ biou, const float* __restrict__ Ufb,
    h16* __restrict__ hUpW, h16* __restrict__ cPar,
    int log2n, int leafLvl, int cbN, int cOff, int ndOff){
  const int n = 1 << log2n;
  const int mask2 = 2*n - 1;
  __shared__ h16 ldsA[4*8*64*8];   // 32 KB
  __shared__ h16 ldsB[16*64*8];    // 16 KB
  const int t = threadIdx.x, w = t >> 6, l = t & 63;
  const int q = l >> 4, li = l & 15;
  const int waveR = w & 1, waveC = w >> 1;
  const int bx = blockIdx.x;

  // ---- stage A once: wave w stages rowFrag R=w, kc=0..7 (frag-order) ----
  {
    const int grow = bx*64 + w*16 + li;
    size_t abase;
    if (leafLvl){
      abase = (size_t)grow * 256;                       // leafH: linear
    } else {
      const int cidx = grow & mask2;
      const int rr   = grow >> (log2n + 1);
      abase = ((size_t)(cOff + cidx)*256 + rr)*256;     // node-major hUp
    }
    #pragma unroll
    for (int kc=0; kc<8; ++kc)
      DMA16(hChild + abase + kc*32 + q*8, &ldsA[(w*8 + kc)*512]);
  }

  for (int cb=0; cb<cbN; ++cb){
    const int cbi = blockIdx.y*cbN + cb;            // 64-col group 0..3
    const int colBase = cbi*64;
    const h16* wfBase = Wfrag + (size_t)cbi*8*16*512 + (size_t)l*8;

    // prologue: DMA B(kc=0)
    #pragma unroll
    for (int i=0; i<4; ++i)
      DMA16(wfBase + ((size_t)(w*4 + i))*512, &ldsB[(w*4 + i)*512]);
    __syncthreads();   // drains A-DMA (cb==0) + B(0) + prior epilogue reads

    f32x4 acc[4][2][2] = {};   // [gate f,i,o,u][rt][ct]
    #pragma unroll
    for (int kc=0; kc<8; ++kc){
      f16x8 aF[2], bF[4][2];
      #pragma unroll
      for (int rt=0; rt<2; ++rt)
        aF[rt] = *(const f16x8*)&ldsA[(((waveR*2 + rt)*8 + kc)*64 + l)*8];
      #pragma unroll
      for (int g=0; g<4; ++g)
        #pragma unroll
        for (int ct=0; ct<2; ++ct)
          bF[g][ct] = *(const f16x8*)&ldsB[((g*4 + waveC*2 + ct)*64 + l)*8];
      __syncthreads();   // all reads done; nothing fresh to drain (cheap)
      if (kc < 7){
        #pragma unroll
        for (int i=0; i<4; ++i)
          DMA16(wfBase + ((size_t)(kc+1)*16 + w*4 + i)*512,
                &ldsB[(w*4 + i)*512]);
      }
      #pragma unroll
      for (int g=0; g<4; ++g)
        #pragma unroll
        for (int rt=0; rt<2; ++rt)
          #pragma unroll
          for (int ct=0; ct<2; ++ct)
            acc[g][rt][ct] = __builtin_amdgcn_mfma_f32_16x16x32_f16(
                aF[rt], bF[g][ct], acc[g][rt][ct], 0,0,0);
      __syncthreads();   // drains B(kc+1) DMA — issued before the MFMA block
    }

    // ---- epilogue (all lane-local; sibling pairs = adjacent C regs) ----
    #pragma unroll
    for (int ct=0; ct<2; ++ct){
      const int c = colBase + waveC*32 + ct*16 + li;
      const float fb  = Ufb[c];
      const float bi_ = biou[c], bo_ = biou[256+c], bu_ = biou[512+c];
      #pragma unroll
      for (int rt=0; rt<2; ++rt){
        #pragma unroll
        for (int pp=0; pp<2; ++pp){
          const int crel = waveR*32 + rt*16 + q*4 + 2*pp;  // even child row (rel)
          const int m = bx*32 + (crel >> 1);               // global parent index
          const int rr2 = m >> log2n;
          const int jn = m & (n - 1);
          const float cl = (float)cChild[(size_t)(bx*64 + crel)*256 + c];
          const float cr = (float)cChild[(size_t)(bx*64 + crel + 1)*256 + c];
          const float fl = sigf(acc[0][rt][ct][2*pp]   + fb);
          const float fr = sigf(acc[0][rt][ct][2*pp+1] + fb);
          const float iv = acc[1][rt][ct][2*pp] + acc[1][rt][ct][2*pp+1] + bi_;
          const float ov = acc[2][rt][ct][2*pp] + acc[2][rt][ct][2*pp+1] + bo_;
          const float uv = acc[3][rt][ct][2*pp] + acc[3][rt][ct][2*pp+1] + bu_;
          const float cnew = sig_mul_tanh(iv, uv) + fl*cl + fr*cr;
          const float hnew = sig_mul_tanh(ov, cnew);
          hUpW[(((size_t)(ndOff + jn))*256 + rr2)*256 + c] = (h16)hnew;
          cPar[((size_t)m)*256 + c] = (h16)cnew;
        }
      }
    }
  }
}

// ------------- rep accumulation (internal nodes, node-major hUp region) -----
__global__ __launch_bounds__(256) void rep_accum(const h16* __restrict__ H,
    float* __restrict__ rep, int nrows, int chunk){
  const int r = blockIdx.y, k = threadIdx.x;
  const int n0 = blockIdx.x * chunk;
  int n1 = n0 + chunk; if (n1 > nrows) n1 = nrows;
  float s = 0.f;
  for (int nd = n0; nd < n1; ++nd)
    s += (float)H[((size_t)nd*256 + r)*HS + k];
  atomicAdd(&rep[r*HS + k], s);
}

// ------------- classifier -------------
__global__ __launch_bounds__(256) void cls_kernel(const float* __restrict__ rep,
    const float* __restrict__ clsw, const float* __restrict__ clsb,
    float* __restrict__ out){
  const int b = blockIdx.x, k = threadIdx.x;
  const float d = fabsf(rep[b*HS + k] - rep[(128+b)*HS + k]) * (1.0f/1023.0f);
  __shared__ float r0[256], r1[256];
  r0[k] = d * clsw[k];
  r1[k] = d * clsw[HS + k];
  __syncthreads();
  for (int off = 128; off > 0; off >>= 1){
    if (k < off){ r0[k] += r0[k+off]; r1[k] += r1[k+off]; }
    __syncthreads();
  }
  if (k == 0){
    out[b*2 + 0] = r0[0] + clsb[0];
    out[b*2 + 1] = r1[0] + clsb[1];
  }
}

extern "C" void kernel_launch(void* const* d_in, const int* in_sizes, int n_in,
                              void* d_out, int out_size, void* d_ws, size_t ws_size,
                              hipStream_t stream){
  const int*   types1 = (const int*)d_in[0];
  const int*   types2 = (const int*)d_in[1];
  const float* emb    = (const float*)d_in[2];
  const float* Wiou   = (const float*)d_in[3];
  const float* Uiou   = (const float*)d_in[4];
  const float* biou   = (const float*)d_in[5];
  const float* Ufw    = (const float*)d_in[6];
  const float* Ufb    = (const float*)d_in[7];
  const float* clsw   = (const float*)d_in[8];
  const float* clsb   = (const float*)d_in[9];
  float* out = (float*)d_out;

  // ---- overlay layout (h16 units). Total 117,506,048 h16 = 235.01 MB ----
  h16* ws      = (h16*)d_ws;
  h16* leafH   = ws;                        // [0, 33554432)  leaf h (tree-major)
  h16* leafC   = ws + 33554432UL;           // [.., 67108864) leaf c; later hUp LOW (nodes 0..254, node-major)
  h16* WxV     = ws + 67108864UL;           // [.., 91684864) WxV; later hUp HIGH (nodes 255..510 local 0..255)
  h16* cA      = ws + 91684864UL;           // 16,777,216
  h16* cB      = ws + 108462080UL;          //  8,388,608; overlays emb16+Wx16
  h16* emb16   = cB;                        //  8,192,000
  h16* Wx16    = cB + 8192000UL;            //    196,608
  float* rep   = (float*)(ws + 116850688UL);//     65,536 fp32
  h16* Wfrag   = ws + 116981760UL;          //    524,288
  h16* W16     = ws;                        //    262,144 (overlays leafH; dead after swizzle_w)
  h16* hUpLow  = leafC;                     // nodes 0..254  (written lvl<=7)
  h16* hUpHigh = WxV;                       // nodes 255..510 (written lvl8)

  convert_all<<<4224, 256, 0, stream>>>(emb, Ufw, Uiou, Wiou, emb16, W16, Wx16, rep);
  swizzle_w<<<256, 256, 0, stream>>>(W16, Wfrag);
  wxv_mfma<<<dim3(500,12), 256, 0, stream>>>(emb16, Wx16, WxV);
  leaf_kernel<<<dim3(8, B2), 256, 0, stream>>>(types1, types2, WxV, biou,
                                               leafH, leafC, rep);

  const h16* cprev = nullptr;
  for (int lvl = 8; lvl >= 0; --lvl){
    const int children = 512 << lvl;        // B2 * 2n
    const int cbN = (lvl >= 6) ? 4 : 1;     // big levels: y=1, col loop in-block
    h16* cout = ((8 - lvl) & 1) ? cB : cA;
    const h16* cin = (lvl == 8) ? leafC : cprev;
    const h16* hin = (lvl == 8) ? leafH : ((lvl == 7) ? hUpHigh : hUpLow);
    h16* hUpW      = (lvl == 8) ? hUpHigh : hUpLow;
    const int cOff  = (lvl == 7) ? 0 : ((1 << (lvl + 1)) - 1); // child node local base (non-leaf)
    const int ndOff = (lvl == 8) ? 0 : ((1 << lvl) - 1);       // output node local base
    level_mfma<<<dim3(children/64, 4/cbN), 256, 0, stream>>>(
        hin, cin, Wfrag, biou, Ufb, hUpW, cout,
        lvl, (lvl == 8) ? 1 : 0, cbN, cOff, ndOff);
    cprev = cout;
  }
  rep_accum<<<dim3(2, B2), 256, 0, stream>>>(hUpLow,  rep, 255, 128);
  rep_accum<<<dim3(2, B2), 256, 0, stream>>>(hUpHigh, rep, 256, 128);
  cls_kernel<<<128, 256, 0, stream>>>(rep, clsw, clsb, out);
}